// Round 1
// baseline (1345.548 us; speedup 1.0000x reference)
//
#include <hip/hip_runtime.h>

// LSTM_26912265077001: 2-layer LSTM (H=51, IN=1), T=512, B=1024, fp32.
// Strategy: persistent kernel, one block per NB=2 batch elements (512 blocks).
// Weights live in per-thread registers (thread r < 204 owns gate-row r of
// W_hh1 / W_ih2 / W_hh2); h-state lives in LDS and is read via broadcast
// ds_read_b128; c-state lives in registers of the 102 update threads.

#define Hs   51
#define HP   52          // padded hidden (52 % 4 == 0, pad element is 0)
#define G4   204         // 4*H gate rows
#define Ts   512
#define Bs   1024
#define NB   2           // batch elements per block
#define NT   256         // threads per block

__device__ __forceinline__ float sig_(float x) {
    return 1.0f / (1.0f + __expf(-x));
}
__device__ __forceinline__ float tanh_(float x) {
    // robust for |x| large: e->inf => 1 ; e->0 => -1
    float e = __expf(2.0f * x);
    return 1.0f - 2.0f / (e + 1.0f);
}

__global__ __launch_bounds__(NT, 2) void lstm2_kernel(
    const float* __restrict__ x,      // (T, B, 1)
    const float* __restrict__ W_ih1,  // (204, 1)
    const float* __restrict__ W_hh1,  // (204, 51)
    const float* __restrict__ b_ih1,  // (204,)
    const float* __restrict__ b_hh1,  // (204,)
    const float* __restrict__ W_ih2,  // (204, 51)
    const float* __restrict__ W_hh2,  // (204, 51)
    const float* __restrict__ b_ih2,  // (204,)
    const float* __restrict__ b_hh2,  // (204,)
    const float* __restrict__ W_lin,  // (1, 51)
    const float* __restrict__ b_lin,  // (1,)
    float* __restrict__ out)          // (B, T)
{
    __shared__ float xs[Ts][NB];      // input slice for this block's batches
    __shared__ float h1s[NB][HP];     // layer-1 hidden (padded, pad col = 0)
    __shared__ float h2s[NB][HP];     // layer-2 hidden
    __shared__ float gs[NB][G4];      // gate pre-activations (reused L1/L2)
    __shared__ float wlin_s[HP];
    __shared__ float blin_s;

    const int tid = threadIdx.x;
    const int bg0 = blockIdx.x * NB;

    // ---- one-time preload: x slice into LDS ----
    #pragma unroll
    for (int i = 0; i < (Ts * NB) / NT; ++i) {
        int idx = tid + i * NT;
        int tt  = idx >> 1;           // idx / NB
        int b   = idx & 1;            // idx % NB
        xs[tt][b] = x[tt * Bs + bg0 + b];
    }
    if (tid < HP) {
        h1s[0][tid] = 0.f; h1s[1][tid] = 0.f;
        h2s[0][tid] = 0.f; h2s[1][tid] = 0.f;
        wlin_s[tid] = (tid < Hs) ? W_lin[tid] : 0.f;
    }
    if (tid == 0) blin_s = b_lin[0];

    // ---- one-time preload: weight rows into registers ----
    float w1[HP], w2[HP], w3[HP];
    float bsum1 = 0.f, bsum2 = 0.f, wih1 = 0.f;
    if (tid < G4) {
        #pragma unroll
        for (int k = 0; k < Hs; ++k) {
            w1[k] = W_hh1[tid * Hs + k];
            w2[k] = W_ih2[tid * Hs + k];
            w3[k] = W_hh2[tid * Hs + k];
        }
        w1[Hs] = 0.f; w2[Hs] = 0.f; w3[Hs] = 0.f;
        bsum1 = b_ih1[tid] + b_hh1[tid];
        bsum2 = b_ih2[tid] + b_hh2[tid];
        wih1  = W_ih1[tid];
    }

    float c1 = 0.f, c2 = 0.f;   // cell state for update threads (tid < 102)
    __syncthreads();

    for (int t = 0; t < Ts; ++t) {
        // ---- Phase A: layer-1 gate matvec (tid<204) ||
        //      output dot for step t-1 on idle threads (tid 204..205) ----
        if (tid < G4) {
            float acc0 = fmaf(wih1, xs[t][0], bsum1);
            float acc1 = fmaf(wih1, xs[t][1], bsum1);
            const float4* ha = (const float4*)(&h1s[0][0]);
            const float4* hb = (const float4*)(&h1s[1][0]);
            #pragma unroll
            for (int k4 = 0; k4 < HP / 4; ++k4) {
                float4 a = ha[k4];
                float4 b = hb[k4];
                acc0 = fmaf(w1[4*k4+0], a.x, acc0);
                acc0 = fmaf(w1[4*k4+1], a.y, acc0);
                acc0 = fmaf(w1[4*k4+2], a.z, acc0);
                acc0 = fmaf(w1[4*k4+3], a.w, acc0);
                acc1 = fmaf(w1[4*k4+0], b.x, acc1);
                acc1 = fmaf(w1[4*k4+1], b.y, acc1);
                acc1 = fmaf(w1[4*k4+2], b.z, acc1);
                acc1 = fmaf(w1[4*k4+3], b.w, acc1);
            }
            gs[0][tid] = acc0;
            gs[1][tid] = acc1;
        } else if (t > 0 && tid < G4 + NB) {
            int b = tid - G4;
            const float4* h4 = (const float4*)(&h2s[b][0]);
            const float4* w4 = (const float4*)(&wlin_s[0]);
            float s = blin_s;
            #pragma unroll
            for (int k4 = 0; k4 < HP / 4; ++k4) {
                float4 a = h4[k4];
                float4 w = w4[k4];
                s += a.x * w.x + a.y * w.y + a.z * w.z + a.w * w.w;
            }
            out[(bg0 + b) * Ts + (t - 1)] = s;
        }
        __syncthreads();

        // ---- Phase B: layer-1 elementwise update (tid < 102) ----
        if (tid < NB * Hs) {
            int b = tid / Hs, j = tid % Hs;
            float gi = gs[b][j];
            float gf = gs[b][Hs + j];
            float gg = gs[b][2 * Hs + j];
            float go = gs[b][3 * Hs + j];
            float iv = sig_(gi);
            float fv = sig_(gf);
            float gv = tanh_(gg);
            float ov = sig_(go);
            c1 = fmaf(fv, c1, iv * gv);
            h1s[b][j] = ov * tanh_(c1);
        }
        __syncthreads();

        // ---- Phase C: layer-2 gate matvec (tid < 204) ----
        if (tid < G4) {
            float acc0 = bsum2, acc1 = bsum2;
            const float4* p10 = (const float4*)(&h1s[0][0]);
            const float4* p11 = (const float4*)(&h1s[1][0]);
            const float4* p20 = (const float4*)(&h2s[0][0]);
            const float4* p21 = (const float4*)(&h2s[1][0]);
            #pragma unroll
            for (int k4 = 0; k4 < HP / 4; ++k4) {
                float4 a0 = p10[k4];
                float4 a1 = p11[k4];
                float4 b0 = p20[k4];
                float4 b1 = p21[k4];
                acc0 = fmaf(w2[4*k4+0], a0.x, acc0);
                acc0 = fmaf(w2[4*k4+1], a0.y, acc0);
                acc0 = fmaf(w2[4*k4+2], a0.z, acc0);
                acc0 = fmaf(w2[4*k4+3], a0.w, acc0);
                acc0 = fmaf(w3[4*k4+0], b0.x, acc0);
                acc0 = fmaf(w3[4*k4+1], b0.y, acc0);
                acc0 = fmaf(w3[4*k4+2], b0.z, acc0);
                acc0 = fmaf(w3[4*k4+3], b0.w, acc0);
                acc1 = fmaf(w2[4*k4+0], a1.x, acc1);
                acc1 = fmaf(w2[4*k4+1], a1.y, acc1);
                acc1 = fmaf(w2[4*k4+2], a1.z, acc1);
                acc1 = fmaf(w2[4*k4+3], a1.w, acc1);
                acc1 = fmaf(w3[4*k4+0], b1.x, acc1);
                acc1 = fmaf(w3[4*k4+1], b1.y, acc1);
                acc1 = fmaf(w3[4*k4+2], b1.z, acc1);
                acc1 = fmaf(w3[4*k4+3], b1.w, acc1);
            }
            gs[0][tid] = acc0;
            gs[1][tid] = acc1;
        }
        __syncthreads();

        // ---- Phase D: layer-2 elementwise update (tid < 102) ----
        if (tid < NB * Hs) {
            int b = tid / Hs, j = tid % Hs;
            float gi = gs[b][j];
            float gf = gs[b][Hs + j];
            float gg = gs[b][2 * Hs + j];
            float go = gs[b][3 * Hs + j];
            float iv = sig_(gi);
            float fv = sig_(gf);
            float gv = tanh_(gg);
            float ov = sig_(go);
            c2 = fmaf(fv, c2, iv * gv);
            h2s[b][j] = ov * tanh_(c2);
        }
        __syncthreads();
    }

    // ---- final output for t = T-1 (h2s is barrier-protected above) ----
    if (tid >= G4 && tid < G4 + NB) {
        int b = tid - G4;
        const float4* h4 = (const float4*)(&h2s[b][0]);
        const float4* w4 = (const float4*)(&wlin_s[0]);
        float s = blin_s;
        #pragma unroll
        for (int k4 = 0; k4 < HP / 4; ++k4) {
            float4 a = h4[k4];
            float4 w = w4[k4];
            s += a.x * w.x + a.y * w.y + a.z * w.z + a.w * w.w;
        }
        out[(bg0 + b) * Ts + (Ts - 1)] = s;
    }
}

extern "C" void kernel_launch(void* const* d_in, const int* in_sizes, int n_in,
                              void* d_out, int out_size, void* d_ws, size_t ws_size,
                              hipStream_t stream) {
    const float* x     = (const float*)d_in[0];
    const float* W_ih1 = (const float*)d_in[1];
    const float* W_hh1 = (const float*)d_in[2];
    const float* b_ih1 = (const float*)d_in[3];
    const float* b_hh1 = (const float*)d_in[4];
    const float* W_ih2 = (const float*)d_in[5];
    const float* W_hh2 = (const float*)d_in[6];
    const float* b_ih2 = (const float*)d_in[7];
    const float* b_hh2 = (const float*)d_in[8];
    const float* W_lin = (const float*)d_in[9];
    const float* b_lin = (const float*)d_in[10];
    float* out = (float*)d_out;

    lstm2_kernel<<<Bs / NB, NT, 0, stream>>>(
        x, W_ih1, W_hh1, b_ih1, b_hh1,
        W_ih2, W_hh2, b_ih2, b_hh2, W_lin, b_lin, out);
}